// Round 6
// baseline (8706.058 us; speedup 1.0000x reference)
//
#include <hip/hip_runtime.h>
#include <math.h>

#define BB 16
#define TT 1024
#define FF 128
#define RR 2048
#define HALFR 1024
#define NBLK 256
#define NTHR 512

typedef __attribute__((ext_vector_type(4))) unsigned int u32x4;
typedef __attribute__((ext_vector_type(8))) short bf16x8;
typedef __attribute__((ext_vector_type(4))) float f32x4;

// ---- coherent (IC-level) memory ops: bypass L1/L2, no fences needed ----
__device__ __forceinline__ u32x4 ldg_sc4u(const unsigned* base, unsigned voff) {
    u32x4 r;
    asm volatile("global_load_dwordx4 %0, %1, %2 sc0 sc1"
                 : "=v"(r) : "v"(voff), "s"(base) : "memory");
    return r;
}
__device__ __forceinline__ void stg_sc1u(unsigned* base, unsigned voff, unsigned v) {
    asm volatile("global_store_dword %0, %1, %2 sc0 sc1"
                 :: "v"(voff), "v"(v), "s"(base) : "memory");
}
__device__ __forceinline__ void wait_vm0() {
    asm volatile("s_waitcnt vmcnt(0)" ::: "memory");
}

__device__ __forceinline__ bf16x8 as_bf16x8(u32x4 u) {
    union { u32x4 u4; bf16x8 b8; } c; c.u4 = u; return c.b8;
}

// split fp32 v -> (hh bits, hl bits), each a bf16 pattern; RTN via +0x8000.
__device__ __forceinline__ void split_bf16(float v, unsigned& hh, unsigned& hl) {
    unsigned uh = (__float_as_uint(v) + 0x8000u) & 0xFFFF0000u;
    float rem = v - __uint_as_float(uh);
    unsigned ul = (__float_as_uint(rem) + 0x8000u) & 0xFFFF0000u;
    hh = uh >> 16; hl = ul >> 16;
}
// pack fp32 into one u32: low16 = bf16(hi part), high16 = bf16(residual)
__device__ __forceinline__ unsigned pack_h(float v) {
    unsigned hh, hl; split_bf16(v, hh, hl);
    return (hl << 16) | hh;
}

// ---------------- init: packed h0 + barrier words ----------------
__global__ void init_state_kernel(unsigned* __restrict__ h, const float* __restrict__ start,
                                  unsigned* __restrict__ bar) {
    int idx = blockIdx.x * blockDim.x + threadIdx.x;
    if (idx < BB * RR) h[idx] = pack_h(start[idx & (RR - 1)]);
    if (idx < 2048) bar[idx] = 0u;
}

// ---------------- persistent MFMA ESN kernel ----------------
// R16 = R15's verified MFMA compute + serial-chain surgery.
//  R15 proved: compute ~0.5us/step (Mfma 2.4%, VALU 4.9%) yet step = 7.1us
//  -> the floor is the latency chain (release hop, IC h-load, store drain,
//  arrive aggregation) + 1-block/CU lack of overlap. Changes:
//  (1) Flattened release: grpEpoch hop DELETED; all blocks spin masterEpoch
//      directly (read-shared IC line). Arrive keeps the proven two-level
//      RMW (16 groups x 16).
//  (2) 256 blocks x 8 owned cols, 2 blocks/CU (launch_bounds(512,4)):
//      restores R10's cross-block slip that hides chain latency. MFMA
//      still N=16 (reads 16 W cols, rbase=min(r0,RR-16)); the 8 unowned
//      cols are redundant compute (free at 2.4% util); epilogue writes
//      only the owned 8.
//  (3) x_{t+1} prefetched right after the vm-drain: HBM latency hides
//      under MFMA+reduce+drain instead of sitting post-release.
//  (4) hold carried in-register (this thread produced it last step);
//      per-step hold load deleted; prologue reads start[er] once.
//  h path + arrive mechanics otherwise byte-for-byte R15 (proven).
__global__ __launch_bounds__(NTHR, 4) void esn_mfma(
    const float* __restrict__ inputs,   // [B,T,F]
    const float* __restrict__ Win,      // [R,F]
    const float* __restrict__ Wrec,     // [R,R]
    const float* __restrict__ bias,     // [R]
    unsigned* __restrict__ hA,          // [B,R] packed
    unsigned* __restrict__ hB,          // [B,R] packed
    float* __restrict__ out,            // [B,T,HALFR]
    unsigned* __restrict__ bar,
    const float* __restrict__ start)
{
    __shared__ __align__(16) float sRed[8 * 256];   // 8 KB

    const int tid  = threadIdx.x;
    const int lane = tid & 63;
    const int wave = tid >> 6;          // 0..7 : K-chunk owner (k in [wave*256, +256))
    const int r0   = blockIdx.x * 8;    // owned cols r0..r0+7
    const int rbase = (r0 > RR - 16) ? (RR - 16) : r0;   // 16-col MFMA window
    const int nOwnLo = r0 - rbase;      // owned n-range start within window (0 or 8)
    const int col  = lane & 15;         // B-operand n / A-operand m (batch)
    const int kg   = lane >> 4;         // k-group 0..3 within each 32-chunk
    const int ksb  = wave * 256;
    const bool projb = (rbase < HALFR);

    // ---- W_rec -> register fragments (once; reused 1024 steps) ----
    bf16x8 Wh[8], Wl[8];
#pragma unroll
    for (int s = 0; s < 8; ++s) {
        const float* wp = Wrec + (size_t)(rbase + col) * RR + ksb + s * 32 + kg * 8;
        const float4 w0 = *(const float4*)wp;
        const float4 w1 = *(const float4*)(wp + 4);
        const float wv[8] = {w0.x, w0.y, w0.z, w0.w, w1.x, w1.y, w1.z, w1.w};
        unsigned hh[8], hl[8];
#pragma unroll
        for (int e = 0; e < 8; ++e) split_bf16(wv[e], hh[e], hl[e]);
        u32x4 ph = { hh[0] | (hh[1] << 16), hh[2] | (hh[3] << 16),
                     hh[4] | (hh[5] << 16), hh[6] | (hh[7] << 16) };
        u32x4 pl = { hl[0] | (hl[1] << 16), hl[2] | (hl[3] << 16),
                     hl[4] | (hl[5] << 16), hl[6] | (hl[7] << 16) };
        Wh[s] = as_bf16x8(ph);
        Wl[s] = as_bf16x8(pl);
    }

    // ---- Win -> register fragments (waves 0-3 of proj blocks; K=128).
    //      Per-lane zero for window cols >= HALFR (in_mask). ----
    bf16x8 Ih = {0,0,0,0,0,0,0,0}, Il = {0,0,0,0,0,0,0,0};
    if (projb && wave < 4 && (rbase + col) < HALFR) {
        const float* ip = Win + (size_t)(rbase + col) * FF + wave * 32 + kg * 8;
        const float4 w0 = *(const float4*)ip;
        const float4 w1 = *(const float4*)(ip + 4);
        const float wv[8] = {w0.x, w0.y, w0.z, w0.w, w1.x, w1.y, w1.z, w1.w};
        unsigned hh[8], hl[8];
#pragma unroll
        for (int e = 0; e < 8; ++e) split_bf16(wv[e], hh[e], hl[e]);
        u32x4 ph = { hh[0] | (hh[1] << 16), hh[2] | (hh[3] << 16),
                     hh[4] | (hh[5] << 16), hh[6] | (hh[7] << 16) };
        u32x4 pl = { hl[0] | (hl[1] << 16), hl[2] | (hl[3] << 16),
                     hl[4] | (hl[5] << 16), hl[6] | (hl[7] << 16) };
        Ih = as_bf16x8(ph);
        Il = as_bf16x8(pl);
    }

    // ---- h-load byte offsets: batch=col, k = ksb + s*32 + kg*8 ----
    unsigned voffH[8][2];
#pragma unroll
    for (int s = 0; s < 8; ++s) {
        const unsigned base = (unsigned)(((col * RR) + ksb + s * 32 + kg * 8) * 4);
        voffH[s][0] = base;
        voffH[s][1] = base + 16;
    }
    // per-lane x base (proj waves): batch=col, f = wave*32 + kg*8
    const size_t xbase = (size_t)col * TT * FF + wave * 32 + kg * 8;
    const bool xldr = projb && (wave < 4);

    // ---- epilogue mapping: tid<128 -> elem (m=tid>>3, owned col tid&7) ----
    const int mE  = tid >> 3;                        // batch (for tid<128)
    const int n16 = nOwnLo + (tid & 7);              // col within 16-window
    const int erc = (tid < 128) ? (rbase + n16) : 0; // clamped absolute col
    const int mEc = (tid < 128) ? mE : 0;
    const float myBias = bias[erc];
    const unsigned eOff = (unsigned)((mEc * RR + erc) * 4);
    // hold carried in-register; seeded from start (h0 broadcast).
    float holdv = start[erc];

    // ---- barrier state: 16 groups x 16 blocks; flattened release ----
    const unsigned g = blockIdx.x & 15u;
    unsigned* grpCnt      = bar + g * 32;
    unsigned* masterCnt   = bar + 16 * 32;
    unsigned* masterEpoch = bar + 17 * 32;

    // x_t for the first step
    float4 xc0 = {0,0,0,0}, xc1 = {0,0,0,0};
    if (xldr) {
        const float* xp = inputs + xbase;
        xc0 = *(const float4*)xp;
        xc1 = *(const float4*)(xp + 4);
    }

    for (int t = 0; t < TT; ++t) {
        const unsigned* hc = (t & 1) ? hB : hA;
        unsigned*       hn = (t & 1) ? hA : hB;

        // 1) Issue all coherent h loads up front (16 in flight).
        u32x4 hld[16];
#pragma unroll
        for (int s = 0; s < 8; ++s) {
            hld[2 * s]     = ldg_sc4u(hc, voffH[s][0]);
            hld[2 * s + 1] = ldg_sc4u(hc, voffH[s][1]);
        }

        // 2) Drain, pin ordering (rule #18).
        wait_vm0();
        __builtin_amdgcn_sched_barrier(0);

        // 3) Prefetch x_{t+1} (normal cached loads): latency hides under
        //    the MFMA + reduce + store-drain below.
        float4 xn0, xn1;
        if (xldr) {
            const int tp1 = (t + 1 < TT) ? (t + 1) : (TT - 1);
            const float* xp = inputs + xbase + (size_t)tp1 * FF;
            xn0 = *(const float4*)xp;
            xn1 = *(const float4*)(xp + 4);
        }

        // 4) MFMA: 3 chains (Wh*hh + Wh*hl + Wl*hh), K=2048 (+128 proj).
        f32x4 accA = {0.f, 0.f, 0.f, 0.f};
        f32x4 accB = {0.f, 0.f, 0.f, 0.f};
        f32x4 accC = {0.f, 0.f, 0.f, 0.f};
#pragma unroll
        for (int s = 0; s < 8; ++s) {
            const u32x4 pa = hld[2 * s];
            const u32x4 pb = hld[2 * s + 1];
            u32x4 ahh = { (pa.x & 0xFFFFu) | (pa.y << 16),
                          (pa.z & 0xFFFFu) | (pa.w << 16),
                          (pb.x & 0xFFFFu) | (pb.y << 16),
                          (pb.z & 0xFFFFu) | (pb.w << 16) };
            u32x4 ahl = { (pa.x >> 16) | (pa.y & 0xFFFF0000u),
                          (pa.z >> 16) | (pa.w & 0xFFFF0000u),
                          (pb.x >> 16) | (pb.y & 0xFFFF0000u),
                          (pb.z >> 16) | (pb.w & 0xFFFF0000u) };
            const bf16x8 Ah = as_bf16x8(ahh);
            const bf16x8 Al = as_bf16x8(ahl);
            accA = __builtin_amdgcn_mfma_f32_16x16x32_bf16(Ah, Wh[s], accA, 0, 0, 0);
            accB = __builtin_amdgcn_mfma_f32_16x16x32_bf16(Al, Wh[s], accB, 0, 0, 0);
            accC = __builtin_amdgcn_mfma_f32_16x16x32_bf16(Ah, Wl[s], accC, 0, 0, 0);
        }
        if (xldr) {
            const float xv[8] = {xc0.x, xc0.y, xc0.z, xc0.w, xc1.x, xc1.y, xc1.z, xc1.w};
            unsigned hh[8], hl[8];
#pragma unroll
            for (int e = 0; e < 8; ++e) split_bf16(xv[e], hh[e], hl[e]);
            u32x4 ph = { hh[0] | (hh[1] << 16), hh[2] | (hh[3] << 16),
                         hh[4] | (hh[5] << 16), hh[6] | (hh[7] << 16) };
            u32x4 pl = { hl[0] | (hl[1] << 16), hl[2] | (hl[3] << 16),
                         hl[4] | (hl[5] << 16), hl[6] | (hl[7] << 16) };
            const bf16x8 Axh = as_bf16x8(ph);
            const bf16x8 Axl = as_bf16x8(pl);
            accA = __builtin_amdgcn_mfma_f32_16x16x32_bf16(Axh, Ih, accA, 0, 0, 0);
            accB = __builtin_amdgcn_mfma_f32_16x16x32_bf16(Axl, Ih, accB, 0, 0, 0);
            accC = __builtin_amdgcn_mfma_f32_16x16x32_bf16(Axh, Il, accC, 0, 0, 0);
        }
        const f32x4 acc = accA + accB + accC;

        // 5) Cross-wave reduce: 8 partial 16x16 tiles -> LDS -> tid<128 sums.
        *(f32x4*)&sRed[wave * 256 + lane * 4] = acc;
        __syncthreads();
        if (tid < 128) {
            const int ridx = ((mE >> 2) * 16 + n16) * 4 + (mE & 3);
            float val = 0.f;
#pragma unroll
            for (int w = 0; w < 8; ++w) val += sRed[w * 256 + ridx];
            const float pre  = val + myBias;
            const float vnew = 0.05f * holdv + 0.95f * tanhf(pre);
            holdv = vnew;                          // next step's hold, in-register
            stg_sc1u(hn, eOff, pack_h(vnew));
            if (erc >= HALFR)
                out[((size_t)mE * TT + t) * HALFR + (erc - HALFR)] = vnew;
        }

        // 6) Drain (h stores + x prefetch + out), block-sync, arrive,
        //    flattened-release spin on masterEpoch.
        wait_vm0();
        __syncthreads();
        if (tid == 0) {
            const unsigned tgt = (unsigned)(t + 1);
            const unsigned old = __hip_atomic_fetch_add(grpCnt, 1u, __ATOMIC_RELAXED,
                                                        __HIP_MEMORY_SCOPE_AGENT);
            if (old == tgt * 16u - 1u) {                   // last arriver in group of 16
                const unsigned mo = __hip_atomic_fetch_add(masterCnt, 1u, __ATOMIC_RELAXED,
                                                           __HIP_MEMORY_SCOPE_AGENT);
                if (mo == tgt * 16u - 1u) {                // last of 16 groups
                    __hip_atomic_store(masterEpoch, tgt, __ATOMIC_RELAXED,
                                       __HIP_MEMORY_SCOPE_AGENT);
                } else {
                    while (__hip_atomic_load(masterEpoch, __ATOMIC_RELAXED,
                                             __HIP_MEMORY_SCOPE_AGENT) < tgt)
                        __builtin_amdgcn_s_sleep(1);
                }
            } else {
                while (__hip_atomic_load(masterEpoch, __ATOMIC_RELAXED,
                                         __HIP_MEMORY_SCOPE_AGENT) < tgt)
                    __builtin_amdgcn_s_sleep(1);
            }
        }
        __syncthreads();

        // rotate x double-buffer
        xc0 = xn0; xc1 = xn1;
    }
}

// ---------------- fallback path (proven R1): fp32, 1024 launches ----------------

__global__ void init_h_kernel(float* __restrict__ h, const float* __restrict__ start) {
    int idx = blockIdx.x * blockDim.x + threadIdx.x;
    if (idx < BB * RR) h[idx] = start[idx & (RR - 1)];
}

__global__ __launch_bounds__(512, 2) void step_kernel(
    const float* __restrict__ inputs, const float* __restrict__ Win,
    const float* __restrict__ Wrec, const float* __restrict__ bias,
    const float* __restrict__ h_cur, float* __restrict__ h_next,
    float* __restrict__ out, int t)
{
    const int tid  = threadIdx.x;
    const int wave = tid >> 6;
    const int half = (tid >> 5) & 1;
    const int kl   = tid & 31;
    const int b    = wave * 2 + half;
    const int r0   = blockIdx.x * 8;

    float acc[8];
#pragma unroll
    for (int r = 0; r < 8; ++r) acc[r] = 0.0f;

    if (r0 < HALFR) {
        const float4 in4 = *reinterpret_cast<const float4*>(
            inputs + ((size_t)b * TT + t) * FF + kl * 4);
#pragma unroll
        for (int r = 0; r < 8; ++r) {
            const float4 w4 = *reinterpret_cast<const float4*>(
                Win + (size_t)(r0 + r) * FF + kl * 4);
            acc[r] += in4.x * w4.x + in4.y * w4.y + in4.z * w4.z + in4.w * w4.w;
        }
    }

    const float* hb = h_cur + (size_t)b * RR;
#pragma unroll 2
    for (int j = 0; j < 16; ++j) {
        const int k = kl * 4 + j * 128;
        const float4 h4 = *reinterpret_cast<const float4*>(hb + k);
#pragma unroll
        for (int r = 0; r < 8; ++r) {
            const float4 w4 = *reinterpret_cast<const float4*>(
                Wrec + (size_t)(r0 + r) * RR + k);
            acc[r] = fmaf(h4.x, w4.x, acc[r]);
            acc[r] = fmaf(h4.y, w4.y, acc[r]);
            acc[r] = fmaf(h4.z, w4.z, acc[r]);
            acc[r] = fmaf(h4.w, w4.w, acc[r]);
        }
    }

#pragma unroll
    for (int r = 0; r < 8; ++r) {
        float v = acc[r];
        v += __shfl_xor(v, 1);  v += __shfl_xor(v, 2);
        v += __shfl_xor(v, 4);  v += __shfl_xor(v, 8);
        v += __shfl_xor(v, 16);
        acc[r] = v;
    }

    __shared__ float red[BB][8];
    if (kl == 0) {
#pragma unroll
        for (int r = 0; r < 8; ++r) red[b][r] = acc[r];
    }
    __syncthreads();

    if (tid < BB * 8) {
        const int rr = tid & 7, bb = tid >> 3;
        const int r  = r0 + rr;
        const float pre = red[bb][rr] + bias[r];
        const float h_old = h_cur[(size_t)bb * RR + r];
        const float hn = 0.05f * h_old + 0.95f * tanhf(pre);
        h_next[(size_t)bb * RR + r] = hn;
        if (r0 >= HALFR) out[((size_t)bb * TT + t) * HALFR + (r - HALFR)] = hn;
    }
}

// ---------------- launch ----------------

extern "C" void kernel_launch(void* const* d_in, const int* in_sizes, int n_in,
                              void* d_out, int out_size, void* d_ws, size_t ws_size,
                              hipStream_t stream) {
    const float* inputs = (const float*)d_in[0];   // [B,T,F]
    const float* Win    = (const float*)d_in[1];   // [R,F]
    const float* Wrec   = (const float*)d_in[2];   // [R,R]
    const float* bias   = (const float*)d_in[3];   // [R]
    const float* start  = (const float*)d_in[4];   // [R]
    float* out = (float*)d_out;                    // [B,T,HALFR]

    unsigned* hA = (unsigned*)d_ws;                // [B,R] packed bf16-pair
    unsigned* hB = hA + (size_t)BB * RR;           // [B,R] packed
    unsigned* bar = hB + (size_t)BB * RR;
    const size_t need = (size_t)BB * RR * 4 * 2 + 8192;

    if (ws_size >= need) {
        init_state_kernel<<<64, 512, 0, stream>>>(hA, start, bar);
        void* args[] = { (void*)&inputs, (void*)&Win, (void*)&Wrec, (void*)&bias,
                         (void*)&hA, (void*)&hB, (void*)&out, (void*)&bar,
                         (void*)&start };
        hipLaunchCooperativeKernel((void*)esn_mfma, dim3(NBLK), dim3(NTHR),
                                   args, 0, stream);
    } else {
        float* fA = (float*)d_ws;
        float* fB = fA + (size_t)BB * RR;
        init_h_kernel<<<(BB * RR + 255) / 256, 256, 0, stream>>>(fA, start);
        for (int t = 0; t < TT; ++t) {
            const float* hcur = (t & 1) ? fB : fA;
            float*       hnxt = (t & 1) ? fA : fB;
            step_kernel<<<256, 512, 0, stream>>>(inputs, Win, Wrec, bias, hcur, hnxt, out, t);
        }
    }
}

// Round 7
// 5123.982 us; speedup vs baseline: 1.6991x; 1.6991x over previous
//
#include <hip/hip_runtime.h>
#include <math.h>

#define BB 16
#define TT 1024
#define FF 128
#define RR 2048
#define HALFR 1024
#define NBLK 256
#define NTHR 512

typedef __attribute__((ext_vector_type(2))) unsigned int u32x2;
typedef __attribute__((ext_vector_type(4))) unsigned int u32x4;
typedef __attribute__((ext_vector_type(8))) short bf16x8;
typedef __attribute__((ext_vector_type(4))) float f32x4;

// ---- coherent (IC-level) memory ops: bypass L1/L2, no fences needed ----
__device__ __forceinline__ u32x4 ldg_sc4u(const unsigned* base, unsigned voff) {
    u32x4 r;
    asm volatile("global_load_dwordx4 %0, %1, %2 sc0 sc1"
                 : "=v"(r) : "v"(voff), "s"(base) : "memory");
    return r;
}
__device__ __forceinline__ u32x2 ldg_sc2u(const unsigned* base, unsigned voff) {
    u32x2 r;
    asm volatile("global_load_dwordx2 %0, %1, %2 sc0 sc1"
                 : "=v"(r) : "v"(voff), "s"(base) : "memory");
    return r;
}
__device__ __forceinline__ void stg_sc1u(unsigned* base, unsigned voff, unsigned v) {
    asm volatile("global_store_dword %0, %1, %2 sc0 sc1"
                 :: "v"(voff), "v"(v), "s"(base) : "memory");
}
__device__ __forceinline__ void wait_vm0() {
    asm volatile("s_waitcnt vmcnt(0)" ::: "memory");
}

__device__ __forceinline__ bf16x8 as_bf16x8(u32x4 u) {
    union { u32x4 u4; bf16x8 b8; } c; c.u4 = u; return c.b8;
}

// split fp32 v -> (hh bits, hl bits), each a bf16 pattern; RTN via +0x8000.
__device__ __forceinline__ void split_bf16(float v, unsigned& hh, unsigned& hl) {
    unsigned uh = (__float_as_uint(v) + 0x8000u) & 0xFFFF0000u;
    float rem = v - __uint_as_float(uh);
    unsigned ul = (__float_as_uint(rem) + 0x8000u) & 0xFFFF0000u;
    hh = uh >> 16; hl = ul >> 16;
}
// pack fp32 into one u32: low16 = bf16(hi part), high16 = bf16(residual)
__device__ __forceinline__ unsigned pack_h(float v) {
    unsigned hh, hl; split_bf16(v, hh, hl);
    return (hl << 16) | hh;
}

// ---------------- init: packed h0 + epoch words ----------------
__global__ void init_state_kernel(unsigned* __restrict__ h, const float* __restrict__ start,
                                  unsigned* __restrict__ bar) {
    int idx = blockIdx.x * blockDim.x + threadIdx.x;
    if (idx < BB * RR) h[idx] = pack_h(start[idx & (RR - 1)]);
    if (idx < 2048) bar[idx] = 0u;
}

// ---------------- persistent MFMA ESN kernel, dataflow-synced ----------------
// R17: BARRIER DELETED -> dataflow epoch protocol.
//  Evidence: compute ~0.5us (Mfma 3%, VALU 8%) yet step ~6-7us across R10-R16
//  regardless of structure. The floor is the two-level RMW barrier: drain ->
//  16 group RMWs -> master RMW chain -> release store -> spin detect -> THEN
//  h loads: ~5-7 serial IC round trips + same-line atomic serialization/step.
//  Protocol: block p, after sc-storing its h cols and vmcnt(0) drain,
//  publishes epoch[p]=t+1 (plain sc store, NO RMW). At loop t a consumer
//  needs exactly: all epochs of its half >= t. That one test gives both
//    (a) h_t fully published (producers publish t after storing h_t), and
//    (b) write-safety of the double buffer: we write h_{t+1} into buffer
//        (t+1)&1, which holds h_{t-1}; epoch_c >= t  ==>  c finished step
//        t-1  ==>  c's reads of h_{t-1} completed (c drained them before
//        its h_t stores and epoch-t publish). A fast block e at loop t+1
//        overwrites OUR read buffer only after observing OUR epoch t+1,
//        which we publish only after our h_t reads are drained. Tight.
//  Producer->consumer latency: 2 IC RTs (publish -> poll-hit -> load); no
//  aggregation, no release fan-out, no atomics; skew absorbed up to 1 step.
//  Poll: wave 0 only (keeps poll traffic ~0.4 GB/ms), one dwordx2/lane over
//  the half's 128 epoch words + __all, then __syncthreads.
//  Partitioning fixes from R16's regression: grid = 2 independent batch-
//  halves x 128 col-blocks of 16 cols: h stores are full 64B lines (R16's
//  8-col windows caused 2x write amplification, WRITE 206->335MB); h reads
//  halved (64KB/block, M=8 real rows; lanes col>=8 feed zeros to MFMA).
//  Compute/dtype identical to R15/R16 (verified absmax): split-bf16, 3 MFMA
//  chains; hold in-register; x_{t+1} issued with the h loads (one drain).
__global__ __launch_bounds__(NTHR, 2) void esn_mfma(
    const float* __restrict__ inputs,   // [B,T,F]
    const float* __restrict__ Win,      // [R,F]
    const float* __restrict__ Wrec,     // [R,R]
    const float* __restrict__ bias,     // [R]
    unsigned* __restrict__ hA,          // [B,R] packed
    unsigned* __restrict__ hB,          // [B,R] packed
    float* __restrict__ out,            // [B,T,HALFR]
    unsigned* __restrict__ bar,         // epoch words: [half][128]
    const float* __restrict__ start)
{
    __shared__ __align__(16) float sRed[8 * 256];   // 8 KB

    const int tid  = threadIdx.x;
    const int lane = tid & 63;
    const int wave = tid >> 6;          // 0..7 : K-chunk owner (k in [wave*256,+256))
    const int bh   = blockIdx.x & 1;    // batch half: batches bh*8 .. bh*8+7
    const int cb   = blockIdx.x >> 1;   // col-block 0..127
    const int rb   = cb * 16;           // owned cols rb..rb+15
    const int col  = lane & 15;         // MFMA n (W col) AND m (batch row)
    const int kg   = lane >> 4;         // k-group 0..3 within each 32-chunk
    const int ksb  = wave * 256;
    const bool projb = (rb < HALFR);    // uniform per block (16-col blocks)
    const bool mreal = (col < 8);       // A-operand rows 8..15 are zero pads

    // ---- W_rec -> register fragments (once; reused 1024 steps) ----
    bf16x8 Wh[8], Wl[8];
#pragma unroll
    for (int s = 0; s < 8; ++s) {
        const float* wp = Wrec + (size_t)(rb + col) * RR + ksb + s * 32 + kg * 8;
        const float4 w0 = *(const float4*)wp;
        const float4 w1 = *(const float4*)(wp + 4);
        const float wv[8] = {w0.x, w0.y, w0.z, w0.w, w1.x, w1.y, w1.z, w1.w};
        unsigned hh[8], hl[8];
#pragma unroll
        for (int e = 0; e < 8; ++e) split_bf16(wv[e], hh[e], hl[e]);
        u32x4 ph = { hh[0] | (hh[1] << 16), hh[2] | (hh[3] << 16),
                     hh[4] | (hh[5] << 16), hh[6] | (hh[7] << 16) };
        u32x4 pl = { hl[0] | (hl[1] << 16), hl[2] | (hl[3] << 16),
                     hl[4] | (hl[5] << 16), hl[6] | (hl[7] << 16) };
        Wh[s] = as_bf16x8(ph);
        Wl[s] = as_bf16x8(pl);
    }

    // ---- Win -> register fragments (waves 0-3 of proj blocks; K=128) ----
    bf16x8 Ih = {0,0,0,0,0,0,0,0}, Il = {0,0,0,0,0,0,0,0};
    const bool xwave = projb && (wave < 4);
    if (xwave) {
        const float* ip = Win + (size_t)(rb + col) * FF + wave * 32 + kg * 8;
        const float4 w0 = *(const float4*)ip;
        const float4 w1 = *(const float4*)(ip + 4);
        const float wv[8] = {w0.x, w0.y, w0.z, w0.w, w1.x, w1.y, w1.z, w1.w};
        unsigned hh[8], hl[8];
#pragma unroll
        for (int e = 0; e < 8; ++e) split_bf16(wv[e], hh[e], hl[e]);
        u32x4 ph = { hh[0] | (hh[1] << 16), hh[2] | (hh[3] << 16),
                     hh[4] | (hh[5] << 16), hh[6] | (hh[7] << 16) };
        u32x4 pl = { hl[0] | (hl[1] << 16), hl[2] | (hl[3] << 16),
                     hl[4] | (hl[5] << 16), hl[6] | (hl[7] << 16) };
        Ih = as_bf16x8(ph);
        Il = as_bf16x8(pl);
    }

    // ---- h-load byte offsets (lanes with col<8): batch bh*8+col ----
    const int batm = bh * 8 + (col & 7);
    unsigned voffH[8][2];
#pragma unroll
    for (int s = 0; s < 8; ++s) {
        const unsigned base = (unsigned)(((batm * RR) + ksb + s * 32 + kg * 8) * 4);
        voffH[s][0] = base;
        voffH[s][1] = base + 16;
    }
    // per-lane x base (proj waves, col<8): batch=batm, f = wave*32 + kg*8
    const size_t xbase = (size_t)batm * TT * FF + wave * 32 + kg * 8;

    // ---- epilogue mapping: tid<256 -> (m=tid>>4, n=tid&15); rows m<8 own ----
    const int mE = tid >> 4;
    const int nE = tid & 15;
    const int eBatch = bh * 8 + (mE & 7);
    const int eCol   = rb + nE;
    const bool ownS  = (tid < 256) && (mE < 8);
    const float myBias = bias[eCol];
    const unsigned eOff = (unsigned)((eBatch * RR + eCol) * 4);
    float holdv = start[eCol];          // in-register h_old (R16-verified)

    // ---- dataflow epoch state ----
    const unsigned pollOff = (unsigned)((bh * 128 + lane * 2) * 4);  // wave-0 poll
    const unsigned epOff   = (unsigned)((bh * 128 + cb) * 4);        // our word

    // x_t for the first step
    float4 xc0 = {0,0,0,0}, xc1 = {0,0,0,0};
    if (xwave && mreal) {
        const float* xp = inputs + xbase;
        xc0 = *(const float4*)xp;
        xc1 = *(const float4*)(xp + 4);
    }

    for (int t = 0; t < TT; ++t) {
        const unsigned tgt = (unsigned)t;
        // 1) Dataflow wait: all 128 epochs of this half >= t. (t=0: free.)
        if (wave == 0) {
            for (;;) {
                u32x2 v = ldg_sc2u(bar, pollOff);
                wait_vm0();
                if (__all((v.x >= tgt) && (v.y >= tgt))) break;
            }
        }
        __syncthreads();

        const unsigned* hc = (t & 1) ? hB : hA;
        unsigned*       hn = (t & 1) ? hA : hB;

        // 2) Issue coherent h loads (col<8 lanes; 16 in flight) + x_{t+1}
        //    (cached) so ONE drain covers both; x latency hides under h's.
        u32x4 hld[16];
        if (mreal) {
#pragma unroll
            for (int s = 0; s < 8; ++s) {
                hld[2 * s]     = ldg_sc4u(hc, voffH[s][0]);
                hld[2 * s + 1] = ldg_sc4u(hc, voffH[s][1]);
            }
        } else {
#pragma unroll
            for (int i = 0; i < 16; ++i) hld[i] = (u32x4){0u, 0u, 0u, 0u};
        }
        float4 xn0 = {0,0,0,0}, xn1 = {0,0,0,0};
        if (xwave && mreal) {
            const int tp1 = (t + 1 < TT) ? (t + 1) : (TT - 1);
            const float* xp = inputs + xbase + (size_t)tp1 * FF;
            xn0 = *(const float4*)xp;
            xn1 = *(const float4*)(xp + 4);
        }

        // 3) Drain, pin ordering (rule #18).
        wait_vm0();
        __builtin_amdgcn_sched_barrier(0);

        // 4) MFMA: 3 chains (Wh*hh + Wh*hl + Wl*hh), K=2048 (+128 proj).
        f32x4 accA = {0.f, 0.f, 0.f, 0.f};
        f32x4 accB = {0.f, 0.f, 0.f, 0.f};
        f32x4 accC = {0.f, 0.f, 0.f, 0.f};
#pragma unroll
        for (int s = 0; s < 8; ++s) {
            const u32x4 pa = hld[2 * s];
            const u32x4 pb = hld[2 * s + 1];
            u32x4 ahh = { (pa.x & 0xFFFFu) | (pa.y << 16),
                          (pa.z & 0xFFFFu) | (pa.w << 16),
                          (pb.x & 0xFFFFu) | (pb.y << 16),
                          (pb.z & 0xFFFFu) | (pb.w << 16) };
            u32x4 ahl = { (pa.x >> 16) | (pa.y & 0xFFFF0000u),
                          (pa.z >> 16) | (pa.w & 0xFFFF0000u),
                          (pb.x >> 16) | (pb.y & 0xFFFF0000u),
                          (pb.z >> 16) | (pb.w & 0xFFFF0000u) };
            const bf16x8 Ah = as_bf16x8(ahh);
            const bf16x8 Al = as_bf16x8(ahl);
            accA = __builtin_amdgcn_mfma_f32_16x16x32_bf16(Ah, Wh[s], accA, 0, 0, 0);
            accB = __builtin_amdgcn_mfma_f32_16x16x32_bf16(Al, Wh[s], accB, 0, 0, 0);
            accC = __builtin_amdgcn_mfma_f32_16x16x32_bf16(Ah, Wl[s], accC, 0, 0, 0);
        }
        if (xwave) {
            const float xv[8] = {xc0.x, xc0.y, xc0.z, xc0.w, xc1.x, xc1.y, xc1.z, xc1.w};
            unsigned hh[8], hl[8];
#pragma unroll
            for (int e = 0; e < 8; ++e) split_bf16(xv[e], hh[e], hl[e]);
            u32x4 ph = { hh[0] | (hh[1] << 16), hh[2] | (hh[3] << 16),
                         hh[4] | (hh[5] << 16), hh[6] | (hh[7] << 16) };
            u32x4 pl = { hl[0] | (hl[1] << 16), hl[2] | (hl[3] << 16),
                         hl[4] | (hl[5] << 16), hl[6] | (hl[7] << 16) };
            const bf16x8 Axh = as_bf16x8(ph);
            const bf16x8 Axl = as_bf16x8(pl);
            accA = __builtin_amdgcn_mfma_f32_16x16x32_bf16(Axh, Ih, accA, 0, 0, 0);
            accB = __builtin_amdgcn_mfma_f32_16x16x32_bf16(Axl, Ih, accB, 0, 0, 0);
            accC = __builtin_amdgcn_mfma_f32_16x16x32_bf16(Axh, Il, accC, 0, 0, 0);
        }
        const f32x4 acc = accA + accB + accC;

        // 5) Cross-wave reduce: 8 partial tiles -> LDS -> tid<256 sums.
        *(f32x4*)&sRed[wave * 256 + lane * 4] = acc;
        __syncthreads();
        if (tid < 256) {
            const int ridx = ((mE >> 2) * 16 + nE) * 4 + (mE & 3);
            float val = 0.f;
#pragma unroll
            for (int w = 0; w < 8; ++w) val += sRed[w * 256 + ridx];
            if (ownS) {
                const float pre  = val + myBias;
                const float vnew = 0.05f * holdv + 0.95f * tanhf(pre);
                holdv = vnew;
                stg_sc1u(hn, eOff, pack_h(vnew));   // 16-col run = full 64B line
                if (eCol >= HALFR)
                    out[((size_t)eBatch * TT + t) * HALFR + (eCol - HALFR)] = vnew;
            }
        }

        // 6) Drain own stores, block-sync (all waves drained), publish epoch.
        wait_vm0();
        __syncthreads();
        if (tid == 0) stg_sc1u(bar, epOff, (unsigned)(t + 1));

        // rotate x double-buffer
        xc0 = xn0; xc1 = xn1;
    }
}

// ---------------- fallback path (proven R1): fp32, 1024 launches ----------------

__global__ void init_h_kernel(float* __restrict__ h, const float* __restrict__ start) {
    int idx = blockIdx.x * blockDim.x + threadIdx.x;
    if (idx < BB * RR) h[idx] = start[idx & (RR - 1)];
}

__global__ __launch_bounds__(512, 2) void step_kernel(
    const float* __restrict__ inputs, const float* __restrict__ Win,
    const float* __restrict__ Wrec, const float* __restrict__ bias,
    const float* __restrict__ h_cur, float* __restrict__ h_next,
    float* __restrict__ out, int t)
{
    const int tid  = threadIdx.x;
    const int wave = tid >> 6;
    const int half = (tid >> 5) & 1;
    const int kl   = tid & 31;
    const int b    = wave * 2 + half;
    const int r0   = blockIdx.x * 8;

    float acc[8];
#pragma unroll
    for (int r = 0; r < 8; ++r) acc[r] = 0.0f;

    if (r0 < HALFR) {
        const float4 in4 = *reinterpret_cast<const float4*>(
            inputs + ((size_t)b * TT + t) * FF + kl * 4);
#pragma unroll
        for (int r = 0; r < 8; ++r) {
            const float4 w4 = *reinterpret_cast<const float4*>(
                Win + (size_t)(r0 + r) * FF + kl * 4);
            acc[r] += in4.x * w4.x + in4.y * w4.y + in4.z * w4.z + in4.w * w4.w;
        }
    }

    const float* hb = h_cur + (size_t)b * RR;
#pragma unroll 2
    for (int j = 0; j < 16; ++j) {
        const int k = kl * 4 + j * 128;
        const float4 h4 = *reinterpret_cast<const float4*>(hb + k);
#pragma unroll
        for (int r = 0; r < 8; ++r) {
            const float4 w4 = *reinterpret_cast<const float4*>(
                Wrec + (size_t)(r0 + r) * RR + k);
            acc[r] = fmaf(h4.x, w4.x, acc[r]);
            acc[r] = fmaf(h4.y, w4.y, acc[r]);
            acc[r] = fmaf(h4.z, w4.z, acc[r]);
            acc[r] = fmaf(h4.w, w4.w, acc[r]);
        }
    }

#pragma unroll
    for (int r = 0; r < 8; ++r) {
        float v = acc[r];
        v += __shfl_xor(v, 1);  v += __shfl_xor(v, 2);
        v += __shfl_xor(v, 4);  v += __shfl_xor(v, 8);
        v += __shfl_xor(v, 16);
        acc[r] = v;
    }

    __shared__ float red[BB][8];
    if (kl == 0) {
#pragma unroll
        for (int r = 0; r < 8; ++r) red[b][r] = acc[r];
    }
    __syncthreads();

    if (tid < BB * 8) {
        const int rr = tid & 7, bb = tid >> 3;
        const int r  = r0 + rr;
        const float pre = red[bb][rr] + bias[r];
        const float h_old = h_cur[(size_t)bb * RR + r];
        const float hn = 0.05f * h_old + 0.95f * tanhf(pre);
        h_next[(size_t)bb * RR + r] = hn;
        if (r0 >= HALFR) out[((size_t)bb * TT + t) * HALFR + (r - HALFR)] = hn;
    }
}

// ---------------- launch ----------------

extern "C" void kernel_launch(void* const* d_in, const int* in_sizes, int n_in,
                              void* d_out, int out_size, void* d_ws, size_t ws_size,
                              hipStream_t stream) {
    const float* inputs = (const float*)d_in[0];   // [B,T,F]
    const float* Win    = (const float*)d_in[1];   // [R,F]
    const float* Wrec   = (const float*)d_in[2];   // [R,R]
    const float* bias   = (const float*)d_in[3];   // [R]
    const float* start  = (const float*)d_in[4];   // [R]
    float* out = (float*)d_out;                    // [B,T,HALFR]

    unsigned* hA = (unsigned*)d_ws;                // [B,R] packed bf16-pair
    unsigned* hB = hA + (size_t)BB * RR;           // [B,R] packed
    unsigned* bar = hB + (size_t)BB * RR;          // epoch words
    const size_t need = (size_t)BB * RR * 4 * 2 + 8192;

    if (ws_size >= need) {
        init_state_kernel<<<64, 512, 0, stream>>>(hA, start, bar);
        void* args[] = { (void*)&inputs, (void*)&Win, (void*)&Wrec, (void*)&bias,
                         (void*)&hA, (void*)&hB, (void*)&out, (void*)&bar,
                         (void*)&start };
        hipLaunchCooperativeKernel((void*)esn_mfma, dim3(NBLK), dim3(NTHR),
                                   args, 0, stream);
    } else {
        float* fA = (float*)d_ws;
        float* fB = fA + (size_t)BB * RR;
        init_h_kernel<<<(BB * RR + 255) / 256, 256, 0, stream>>>(fA, start);
        for (int t = 0; t < TT; ++t) {
            const float* hcur = (t & 1) ? fB : fA;
            float*       hnxt = (t & 1) ? fA : fB;
            step_kernel<<<256, 512, 0, stream>>>(inputs, Win, Wrec, bias, hcur, hnxt, out, t);
        }
    }
}